// Round 1
// baseline (255.141 us; speedup 1.0000x reference)
//
#include <hip/hip_runtime.h>
#include <hip/hip_bf16.h>

// Problem constants
#define NB 16384      // batch rows
#define DIN 256
#define DOUT 256
#define DD 512        // IN+OUT
#define NCELL 4
#define NCOLS 4096    // 4*OUT*NCELL

typedef __attribute__((ext_vector_type(8))) short short8;
typedef __attribute__((ext_vector_type(4))) float f32x4;

__device__ __forceinline__ float sigmoidf_(float x) {
    return 1.f / (1.f + __expf(-x));
}
__device__ __forceinline__ float tanhf_(float x) {
    float e = __expf(-2.f * fabsf(x));      // in (0,1], no overflow
    float t = (1.f - e) / (1.f + e);
    return copysignf(t, x);
}

#define GLOAD_LDS16(g, l) __builtin_amdgcn_global_load_lds( \
    (__attribute__((address_space(1))) void*)(g), \
    (__attribute__((address_space(3))) void*)(l), 16, 0, 0)

// ---------------- P1: feats (concat x,h) -> bf16 ----------------
__global__ void k_feats_bf16(const float* __restrict__ x, const float* __restrict__ h,
                             __hip_bfloat16* __restrict__ featsB) {
    int t = blockIdx.x * blockDim.x + threadIdx.x;   // 1,048,576 threads
    int idx = t * 8;
    int row = idx >> 9;
    int k = idx & 511;
    const float* src = (k < 256) ? (x + (size_t)row * 256 + k)
                                 : (h + (size_t)row * 256 + (k - 256));
    float4 a = ((const float4*)src)[0];
    float4 b = ((const float4*)src)[1];
    __hip_bfloat16 tmp[8];
    tmp[0] = __float2bfloat16(a.x); tmp[1] = __float2bfloat16(a.y);
    tmp[2] = __float2bfloat16(a.z); tmp[3] = __float2bfloat16(a.w);
    tmp[4] = __float2bfloat16(b.x); tmp[5] = __float2bfloat16(b.y);
    tmp[6] = __float2bfloat16(b.z); tmp[7] = __float2bfloat16(b.w);
    *reinterpret_cast<short8*>(featsB + idx) = *reinterpret_cast<short8*>(tmp);
}

// ---------------- P2: W_gates -> bf16, permuted + transposed ----------------
// W2 layout: [c2g][k], c2g = o_blk*256 + (cell*4+gate)*16 + oi   (4096 x 512 bf16)
__global__ void k_repack_w(const float* __restrict__ Wg, __hip_bfloat16* __restrict__ W2) {
    int t = blockIdx.x * blockDim.x + threadIdx.x;   // 262,144 threads
    int c2g = t >> 6;
    int k0 = (t & 63) * 8;
    int oi = c2g & 15;
    int cg = (c2g >> 4) & 15;
    int o_blk = c2g >> 8;
    int cell = cg >> 2, gate = cg & 3;
    int col = cell * 1024 + gate * 256 + o_blk * 16 + oi;
    __hip_bfloat16 tmp[8];
#pragma unroll
    for (int j = 0; j < 8; ++j)
        tmp[j] = __float2bfloat16(Wg[(size_t)(k0 + j) * 4096 + col]);
    *reinterpret_cast<short8*>(W2 + (size_t)c2g * 512 + k0) = *reinterpret_cast<short8*>(tmp);
}

// ---------------- P3: ctrl logits (f32) + top-2 softmax gates ----------------
__global__ void k_gates(const float* __restrict__ x, const float* __restrict__ h,
                        const float* __restrict__ Wc, const float* __restrict__ bc,
                        float* __restrict__ gates) {
    int gw = (blockIdx.x * blockDim.x + threadIdx.x) >> 6;  // wave id == row
    int lane = threadIdx.x & 63;
    int row = gw;
    int k0 = lane * 8;
    const float* src = (k0 < 256) ? (x + (size_t)row * 256 + k0)
                                  : (h + (size_t)row * 256 + k0 - 256);
    float4 f0 = ((const float4*)src)[0];
    float4 f1 = ((const float4*)src)[1];
    float fv[8] = {f0.x, f0.y, f0.z, f0.w, f1.x, f1.y, f1.z, f1.w};
    float acc[4] = {0.f, 0.f, 0.f, 0.f};
#pragma unroll
    for (int j = 0; j < 8; ++j) {
        float4 w = ((const float4*)Wc)[k0 + j];   // W_ctrl row (k0+j): 4 cells
        acc[0] += fv[j] * w.x; acc[1] += fv[j] * w.y;
        acc[2] += fv[j] * w.z; acc[3] += fv[j] * w.w;
    }
#pragma unroll
    for (int off = 32; off; off >>= 1) {
#pragma unroll
        for (int c = 0; c < 4; ++c) acc[c] += __shfl_xor(acc[c], off);
    }
    if (lane == 0) {
        float l[4];
#pragma unroll
        for (int c = 0; c < 4; ++c) l[c] = acc[c] + bc[c];
        int i1 = 0;
#pragma unroll
        for (int c = 1; c < 4; ++c) if (l[c] > l[i1]) i1 = c;   // ties -> lowest idx
        int i2 = -1;
#pragma unroll
        for (int c = 0; c < 4; ++c)
            if (c != i1 && (i2 < 0 || l[c] > l[i2])) i2 = c;
        float e = __expf(l[i2] - l[i1]);   // <= 1
        float p1 = 1.f / (1.f + e);
        float p2 = e / (1.f + e);
        float g[4] = {0.f, 0.f, 0.f, 0.f};
        g[i1] = p1; g[i2] = p2;
        float4 gv; gv.x = g[0]; gv.y = g[1]; gv.z = g[2]; gv.w = g[3];
        *(float4*)(gates + (size_t)row * 4) = gv;
    }
}

// ---------------- Main fused GEMM + LSTM epilogue ----------------
#define BM 128
#define BN 256
#define BK 64

__launch_bounds__(512, 1)
__global__ void k_main(const __hip_bfloat16* __restrict__ featsB,
                       const __hip_bfloat16* __restrict__ W2,
                       const float* __restrict__ cin,
                       const float* __restrict__ gates,
                       const float* __restrict__ bg,
                       float* __restrict__ out) {
    __shared__ __hip_bfloat16 As[BM * BK];   // [row][k]   16KB
    __shared__ __hip_bfloat16 Bs[BN * BK];   // [c2][k]    32KB
    __shared__ float cTile[BM * 16];         // 8KB
    __shared__ float gTile[BM * 4];          // 2KB
    __shared__ float oAcc[2 * BM * 16];      // 16KB  (nh | nc)

    int tid = threadIdx.x;
    int wave = tid >> 6, lane = tid & 63;
    int wr = wave >> 2, wc = wave & 3;       // wc == cell index
    int r0 = blockIdx.x * BM;
    int o_blk = blockIdx.y;

    // preload c-slice, gate weights; zero output accumulator
    {
        int r = tid >> 2;
        int q = tid & 3;
        *(float4*)&cTile[r * 16 + q * 4] =
            *(const float4*)&cin[(size_t)(r0 + r) * 256 + o_blk * 16 + q * 4];
        gTile[r * 4 + q] = gates[(size_t)(r0 + r) * 4 + q];
    }
    for (int i = tid; i < 2 * BM * 16; i += 512) oAcc[i] = 0.f;

    f32x4 acc[4][4];
#pragma unroll
    for (int m = 0; m < 4; ++m)
#pragma unroll
        for (int n = 0; n < 4; ++n)
            acc[m][n] = (f32x4){0.f, 0.f, 0.f, 0.f};

    for (int ks = 0; ks < 8; ++ks) {
        int k0 = ks * BK;
        // stage A: 128x64 bf16, lane-linear
#pragma unroll
        for (int q = 0; q < 2; ++q) {
            int e = (q * 512 + tid) * 8;
            int r = e >> 6, kk = e & 63;
            GLOAD_LDS16(featsB + (size_t)(r0 + r) * 512 + k0 + kk, As + e);
        }
        // stage B: 256x64 bf16 (c2-major)
#pragma unroll
        for (int q = 0; q < 4; ++q) {
            int e = (q * 512 + tid) * 8;
            int c2 = e >> 6, kk = e & 63;
            GLOAD_LDS16(W2 + (size_t)(o_blk * 256 + c2) * 512 + k0 + kk, Bs + e);
        }
        __syncthreads();   // drains vmcnt + barrier
#pragma unroll
        for (int kk = 0; kk < 2; ++kk) {
            int klane = kk * 32 + (lane >> 4) * 8;
            short8 fa[4], fb[4];
#pragma unroll
            for (int m = 0; m < 4; ++m) {
                int row = wr * 64 + m * 16 + (lane & 15);
                fa[m] = *reinterpret_cast<const short8*>(As + row * BK + klane);
            }
#pragma unroll
            for (int n = 0; n < 4; ++n) {
                int c2 = wc * 64 + n * 16 + (lane & 15);
                fb[n] = *reinterpret_cast<const short8*>(Bs + c2 * BK + klane);
            }
#pragma unroll
            for (int m = 0; m < 4; ++m)
#pragma unroll
                for (int n = 0; n < 4; ++n)
                    acc[m][n] = __builtin_amdgcn_mfma_f32_16x16x32_bf16(
                        fa[m], fb[n], acc[m][n], 0, 0, 0);
        }
        __syncthreads();
    }

    // Epilogue: wave wc handles cell wc; acc[m][g][reg] = combined(row, gate g)
    int oi = lane & 15;
    float bb0 = bg[wc * 1024 + 0 * 256 + o_blk * 16 + oi];
    float bb1 = bg[wc * 1024 + 1 * 256 + o_blk * 16 + oi];
    float bb2 = bg[wc * 1024 + 2 * 256 + o_blk * 16 + oi];
    float bb3 = bg[wc * 1024 + 3 * 256 + o_blk * 16 + oi];

#pragma unroll
    for (int m = 0; m < 4; ++m) {
#pragma unroll
        for (int reg = 0; reg < 4; ++reg) {
            int r = wr * 64 + m * 16 + ((lane >> 4) << 2) + reg;
            float gw = gTile[r * 4 + wc];
            if (gw != 0.f) {
                float iv = sigmoidf_(acc[m][0][reg] + bb0);
                float jv = acc[m][1][reg] + bb1;
                float fv = sigmoidf_(acc[m][2][reg] + bb2);
                float ov = sigmoidf_(acc[m][3][reg] + bb3);
                float cv = cTile[r * 16 + oi];
                float ncl = fv * cv + iv * tanhf_(jv);
                float nhl = ov * tanhf_(ncl);
                atomicAdd(&oAcc[r * 16 + oi], gw * nhl);
                atomicAdd(&oAcc[BM * 16 + r * 16 + oi], gw * ncl);
            }
        }
    }
    __syncthreads();
    {
        int r = tid >> 2, q = tid & 3;
        size_t ob = (size_t)(r0 + r) * 256 + o_blk * 16 + q * 4;
        *(float4*)&out[ob] = *(float4*)&oAcc[r * 16 + q * 4];
        *(float4*)&out[(size_t)NB * 256 + ob] = *(float4*)&oAcc[BM * 16 + r * 16 + q * 4];
    }
}

extern "C" void kernel_launch(void* const* d_in, const int* in_sizes, int n_in,
                              void* d_out, int out_size, void* d_ws, size_t ws_size,
                              hipStream_t stream) {
    const float* x  = (const float*)d_in[0];
    const float* c  = (const float*)d_in[1];
    const float* h  = (const float*)d_in[2];
    const float* Wg = (const float*)d_in[3];
    const float* bg = (const float*)d_in[4];
    const float* Wc = (const float*)d_in[5];
    const float* bc = (const float*)d_in[6];
    float* out = (float*)d_out;

    const size_t featsB_bytes = (size_t)NB * DD * 2;        // 16.78 MB
    const size_t w2_bytes     = (size_t)NCOLS * DD * 2;     // 4.19 MB
    const size_t gates_bytes  = (size_t)NB * 4 * 4;         // 0.26 MB
    if (ws_size < featsB_bytes + w2_bytes + gates_bytes) return;

    char* ws = (char*)d_ws;
    __hip_bfloat16* featsB = (__hip_bfloat16*)ws;
    __hip_bfloat16* W2     = (__hip_bfloat16*)(ws + featsB_bytes);
    float*          gatesW = (float*)(ws + featsB_bytes + w2_bytes);

    k_feats_bf16<<<dim3(4096), dim3(256), 0, stream>>>(x, h, featsB);
    k_repack_w<<<dim3(1024), dim3(256), 0, stream>>>(Wg, W2);
    k_gates<<<dim3(4096), dim3(256), 0, stream>>>(x, h, Wc, bc, gatesW);
    k_main<<<dim3(NB / BM, 16), dim3(512), 0, stream>>>(featsB, W2, c, gatesW, bg, out);
}